// Round 4
// baseline (332.630 us; speedup 1.0000x reference)
//
#include <hip/hip_runtime.h>

// 3-level db4 band-split. R5: LDS-instruction-minimized, barrier-free waves.
// Theory: R2/R3/R4 all ~same time because per-CU LDS instruction issue
// (~90 ds ops/wave x 256 waves/CU x ~6-8cyc = ~65us) exceeds the HBM floor
// (~57us). This version cuts LDS ops to ~40/wave for interior waves (94%):
//  - level-1 (x->a1,d1) fused into level-2 and into the o3 band: x, a1, d1
//    never touch LDS; reads are aligned float4 from global (L1-served overlap).
//  - upsample-convs widened: 2 pairs/lane, reads 2xb64+1xb32, writes 1xb128.
// Edge waves (first/last tile per row) keep the R4 reflected-LDS path.
// No __syncthreads anywhere (wave-autonomous tiles, 4 waves/block).

#define T      256
#define N0     8192
#define L1     4099
#define L2     2053
#define L3     1030
#define NROWS  2048
#define TW     256
#define WSLICE 960

#define RL0 0.23037781330885523f
#define RL1 0.7148465705525415f
#define RL2 0.6308807679295904f
#define RL3 (-0.02798376941698385f)
#define RL4 (-0.18703481171888114f)
#define RL5 0.030841381835986965f
#define RL6 0.032883011666982945f
#define RL7 (-0.010597401784997278f)

__device__ __forceinline__ int reflect(int m, int n)
{
    m = (m < 0) ? (-1 - m) : m;
    m = (m >= n) ? (2 * n - 1 - m) : m;
    return m;
}

// Forward DWT window (LDS->LDS), reflected-slot scheme (R4-proven).
__device__ __forceinline__ void fwd_win(const float* __restrict__ src, int src_lo,
                                        float* __restrict__ dstA, float* __restrict__ dstD,
                                        int out_lo, int out_len, int Lv, int lane)
{
    const float lo[8] = {RL0, RL1, RL2, RL3, RL4, RL5, RL6, RL7};
    const float hi[8] = {RL7, -RL6, RL5, -RL4, RL3, -RL2, RL1, -RL0};
    const float2* s2 = (const float2*)src;
    for (int idx = lane; idx < out_len; idx += 64) {
        int g  = out_lo + idx;
        int ge = reflect(g, Lv);
        int h  = (2 * ge - 6 - src_lo) >> 1;
        float2 p0 = s2[h], p1 = s2[h + 1], p2 = s2[h + 2], p3 = s2[h + 3];
        float w[8] = {p0.x, p0.y, p1.x, p1.y, p2.x, p2.y, p3.x, p3.y};
        float sa = 0.f, sd = 0.f;
#pragma unroll
        for (int k = 0; k < 8; ++k) {
            sa = fmaf(w[k], lo[k], sa);
            sd = fmaf(w[k], hi[k], sd);
        }
        dstA[idx] = sa;
        dstD[idx] = sd;
    }
}

// Final upsample-conv to global: lane produces n = w0+4*lane .. +3 (one float4).
__device__ __forceinline__ void fin_win(const float* __restrict__ src, int src_lo, int w0,
                                        float* __restrict__ g,
                                        float o0, float o1, float o2, float o3,
                                        float e0, float e1, float e2, float e3, int lane)
{
    int b = (w0 >> 1) + 2 * lane - src_lo;
    const float2* s2 = (const float2*)src;
    float2 q0 = s2[b >> 1], q1 = s2[(b >> 1) + 1];
    float s4 = src[b + 4];
    float a0 = q0.x, a1 = q0.y, a2 = q1.x, a3 = q1.y;
    float4 o;
    o.x = a0 * e0 + a1 * e1 + a2 * e2 + a3 * e3;
    o.y = a0 * o0 + a1 * o1 + a2 * o2 + a3 * o3;
    o.z = a1 * e0 + a2 * e1 + a3 * e2 + s4 * e3;
    o.w = a1 * o0 + a2 * o1 + a3 * o2 + s4 * o3;
    ((float4*)(g + w0))[lane] = o;
}

// Widened upsample-conv LDS->LDS: each active lane does 2 pairs (4 outputs):
// reads src slots [2*lane .. 2*lane+4] (2x b64 + 1x b32), writes 1x b128.
// Requires t0 == src window base (true for all call sites) so b is even.
__device__ __forceinline__ void up2_win(const float* __restrict__ src, int src_lo,
                                        float* __restrict__ dst, int t0, int pairs,
                                        float o0, float o1, float o2, float o3,
                                        float e0, float e1, float e2, float e3, int lane)
{
    const float2* s2 = (const float2*)src;
    const int half = pairs >> 1;
    if (lane < half) {
        const int b = t0 + 2 * lane - src_lo;      // even
        float2 q0 = s2[b >> 1], q1 = s2[(b >> 1) + 1];
        float s4 = src[b + 4];
        float a0 = q0.x, a1 = q0.y, a2 = q1.x, a3 = q1.y;
        float4 r;
        r.x = a0 * e0 + a1 * e1 + a2 * e2 + a3 * e3;
        r.y = a0 * o0 + a1 * o1 + a2 * o2 + a3 * o3;
        r.z = a1 * e0 + a2 * e1 + a3 * e2 + s4 * e3;
        r.w = a1 * o0 + a2 * o1 + a3 * o2 + s4 * o3;
        ((float4*)dst)[lane] = r;
    } else if ((pairs & 1) && lane == half) {      // odd tail pair
        const int p = pairs - 1;                   // even
        const int b = t0 + p - src_lo;
        float2 q0 = s2[b >> 1], q1 = s2[(b >> 1) + 1];
        float ev = q0.x * e0 + q0.y * e1 + q1.x * e2 + q1.y * e3;
        float od = q0.x * o0 + q0.y * o1 + q1.x * o2 + q1.y * o3;
        ((float2*)dst)[p] = make_float2(ev, od);
    }
}

// Fused d1 + final: o3 band straight from global x (interior waves only).
// Lane computes o3[w0+4*lane .. +3] from d1[m0..m0+4], m0 = w0/2+2*lane,
// each d1 from x[2m-6..2m+1]. x window = [w0+4l-8, w0+4l+12) aligned float4.
__device__ __forceinline__ void o3_fused(const float* __restrict__ xr, int w0,
                                         float* __restrict__ o3p, int lane)
{
    const float hi[8] = {RL7, -RL6, RL5, -RL4, RL3, -RL2, RL1, -RL0};
    const float4* x4 = (const float4*)xr;
    const int q0 = (w0 + 4 * lane - 8) >> 2;
    float f[20];
#pragma unroll
    for (int q = 0; q < 5; ++q)
        *(float4*)&f[4 * q] = x4[q0 + q];
    float dm[5];
#pragma unroll
    for (int j = 0; j < 5; ++j) {
        float s = 0.f;
#pragma unroll
        for (int t = 0; t < 8; ++t) s = fmaf(f[2 + 2 * j + t], hi[t], s);
        dm[j] = s;
    }
    const float e0 = RL1, e1 = RL3, e2 = RL5, e3 = RL7;
    const float p0 = -RL0, p1 = -RL2, p2 = -RL4, p3 = -RL6;
    float4 r;
    r.x = dm[0] * e0 + dm[1] * e1 + dm[2] * e2 + dm[3] * e3;
    r.y = dm[0] * p0 + dm[1] * p1 + dm[2] * p2 + dm[3] * p3;
    r.z = dm[1] * e0 + dm[2] * e1 + dm[3] * e2 + dm[4] * e3;
    r.w = dm[1] * p0 + dm[2] * p1 + dm[3] * p2 + dm[4] * p3;
    ((float4*)(o3p + w0))[lane] = r;
}

// Fused level-1+2: a2w/d2w slots [0,84) straight from global x (interior).
// a2[i],d2[i] need a1[2i-6..2i+1]; each a1 from 8 x taps ->
// x window [4i-18, 4i+4), loaded as 6 aligned float4 from x[4i-20].
__device__ __forceinline__ void lvl2_fused(const float* __restrict__ xr, int lo2,
                                           float* __restrict__ a2w,
                                           float* __restrict__ d2w, int lane)
{
    const float lo[8] = {RL0, RL1, RL2, RL3, RL4, RL5, RL6, RL7};
    const float hi[8] = {RL7, -RL6, RL5, -RL4, RL3, -RL2, RL1, -RL0};
    const float4* x4 = (const float4*)xr;
    for (int idx = lane; idx < 84; idx += 64) {
        const int i  = lo2 + idx;
        const int q0 = i - 5;                  // float4 index of x[4i-20]
        float f[24];
#pragma unroll
        for (int q = 0; q < 6; ++q)
            *(float4*)&f[4 * q] = x4[q0 + q];
        float a1v[8];
#pragma unroll
        for (int k = 0; k < 8; ++k) {
            float s = 0.f;
#pragma unroll
            for (int j = 0; j < 8; ++j) s = fmaf(f[2 + 2 * k + j], lo[j], s);
            a1v[k] = s;
        }
        float sa = 0.f, sd = 0.f;
#pragma unroll
        for (int k = 0; k < 8; ++k) {
            sa = fmaf(a1v[k], lo[k], sa);
            sd = fmaf(a1v[k], hi[k], sd);
        }
        a2w[idx] = sa;
        d2w[idx] = sd;
    }
}

// Per-wave LDS slice (floats; offsets mult-of-4 where b128 targets, even for b64):
//   xw  [0,360)   a1w [360,534)   d1w [534,708)    (edge waves only)
//   a2w [708,792) d2w [792,876)   a3w [876,916)    d3w [916,955)
//   t2  [0,132)   t1a [136,206)   t1d [208,278)
//   t2a [360,492) t2d [536,668)
__global__ __launch_bounds__(T) void wavelet_bands(const float* __restrict__ x,
                                                   float* __restrict__ out)
{
    __shared__ __align__(16) float buf[4 * WSLICE];
    const int tid  = threadIdx.x;
    const int lane = tid & 63;
    const int wid  = tid >> 6;
    const int bid  = blockIdx.x;
    const int row  = bid >> 3;
    const int w0   = ((bid & 7) * 4 + wid) * TW;

    float* wbuf = buf + wid * WSLICE;
    float* xw  = wbuf;
    float* a1w = wbuf + 360;
    float* d1w = wbuf + 534;
    float* a2w = wbuf + 708;
    float* d2w = wbuf + 792;
    float* a3w = wbuf + 876;
    float* d3w = wbuf + 916;
    float* t2  = wbuf;
    float* t1a = wbuf + 136;
    float* t1d = wbuf + 208;
    float* t2a = wbuf + 360;
    float* t2d = wbuf + 536;

    const int lo1 = (w0 >> 1) - 18;
    const int lo2 = (w0 >> 2) - 6;
    const int lo3 = (w0 >> 3);
    const int lox = w0 - 48;

    const float* xr = x + (size_t)row * N0;
    const size_t band = (size_t)NROWS * N0;
    float* o0p = out + (size_t)row * N0;   // a3 band
    float* o1p = o0p + band;               // d3
    float* o2p = o0p + 2 * band;           // d2
    float* o3p = o0p + 3 * band;           // d1

    if (w0 == 0 || w0 == N0 - TW) {
        // Edge path (2/32 waves): R4 reflected-LDS pipeline for levels 1-2 + o3.
        for (int idx = lane; idx < 360; idx += 64)
            xw[idx] = xr[reflect(lox + idx, N0)];
        fwd_win(xw, lox, a1w, d1w, lo1, TW / 2 + 46, L1, lane);
        fwd_win(a1w, lo1, a2w, d2w, lo2, TW / 4 + 20, L2, lane);
        fin_win(d1w, lo1, w0, o3p, -RL0, -RL2, -RL4, -RL6, RL1, RL3, RL5, RL7, lane);
    } else {
        // Interior path (30/32 waves): no LDS for x/a1/d1 at all.
        o3_fused(xr, w0, o3p, lane);
        lvl2_fused(xr, lo2, a2w, d2w, lane);
    }

    // Common tail (all waves), wave-internal deps only.
    // level-3 forward: a2w -> a3w,d3w
    fwd_win(a2w, lo2, a3w, d3w, lo3, TW / 8 + 7, L3, lane);
    // d2 stage-1: up_HI(d2w) -> t2
    up2_win(d2w, lo2, t2, w0 >> 2, TW / 4 + 2, -RL0, -RL2, -RL4, -RL6, RL1, RL3, RL5, RL7, lane);

    // d2 band final -> o2  ||  up_LO(a3) -> t1a  ||  up_HI(d3) -> t1d
    fin_win(t2, w0 >> 1, w0, o2p, RL7, RL5, RL3, RL1, RL6, RL4, RL2, RL0, lane);
    up2_win(a3w, lo3, t1a, w0 >> 3, TW / 8 + 3, RL7, RL5, RL3, RL1, RL6, RL4, RL2, RL0, lane);
    up2_win(d3w, lo3, t1d, w0 >> 3, TW / 8 + 3, -RL0, -RL2, -RL4, -RL6, RL1, RL3, RL5, RL7, lane);

    // stage-2 ups
    up2_win(t1a, w0 >> 2, t2a, w0 >> 2, TW / 4 + 2, RL7, RL5, RL3, RL1, RL6, RL4, RL2, RL0, lane);
    up2_win(t1d, w0 >> 2, t2d, w0 >> 2, TW / 4 + 2, RL7, RL5, RL3, RL1, RL6, RL4, RL2, RL0, lane);

    // finals
    fin_win(t2a, w0 >> 1, w0, o0p, RL7, RL5, RL3, RL1, RL6, RL4, RL2, RL0, lane);
    fin_win(t2d, w0 >> 1, w0, o1p, RL7, RL5, RL3, RL1, RL6, RL4, RL2, RL0, lane);
}

extern "C" void kernel_launch(void* const* d_in, const int* in_sizes, int n_in,
                              void* d_out, int out_size, void* d_ws, size_t ws_size,
                              hipStream_t stream)
{
    const float* x = (const float*)d_in[0];
    float* out = (float*)d_out;
    wavelet_bands<<<NROWS * 8, T, 0, stream>>>(x, out);
}

// Round 5
// 316.720 us; speedup vs baseline: 1.0502x; 1.0502x over previous
//
#include <hip/hip_runtime.h>

// 3-level db4 band-split. R6 = R4 (barrier-free wave-autonomous tiles, LDS-staged
// levels) + the verified-correct up2_win widening from R5 (2 pairs/lane,
// b64/b128 LDS accesses). R5's global-fusion (lvl2_fused/o3_fused) REVERTED:
// it traded 2 global loads/lane for ~17 and +80 FMA/output -> +21us regression.
// One wave owns one 256-sample tile end-to-end; no __syncthreads anywhere.
// 16384 blocks x 256 thr (4 waves), 15.36 KB LDS/block -> 8 blocks/CU = 32 w/CU.

#define T      256
#define N0     8192
#define L1     4099
#define L2     2053
#define L3     1030
#define NROWS  2048
#define TW     256
#define WSLICE 960

#define RL0 0.23037781330885523f
#define RL1 0.7148465705525415f
#define RL2 0.6308807679295904f
#define RL3 (-0.02798376941698385f)
#define RL4 (-0.18703481171888114f)
#define RL5 0.030841381835986965f
#define RL6 0.032883011666982945f
#define RL7 (-0.010597401784997278f)

__device__ __forceinline__ int reflect(int m, int n)
{
    m = (m < 0) ? (-1 - m) : m;
    m = (m >= n) ? (2 * n - 1 - m) : m;
    return m;
}

// Forward DWT window (LDS->LDS), reflected-slot scheme (R4-proven).
__device__ __forceinline__ void fwd_win(const float* __restrict__ src, int src_lo,
                                        float* __restrict__ dstA, float* __restrict__ dstD,
                                        int out_lo, int out_len, int Lv, int lane)
{
    const float lo[8] = {RL0, RL1, RL2, RL3, RL4, RL5, RL6, RL7};
    const float hi[8] = {RL7, -RL6, RL5, -RL4, RL3, -RL2, RL1, -RL0};
    const float2* s2 = (const float2*)src;
    for (int idx = lane; idx < out_len; idx += 64) {
        int g  = out_lo + idx;
        int ge = reflect(g, Lv);
        int h  = (2 * ge - 6 - src_lo) >> 1;
        float2 p0 = s2[h], p1 = s2[h + 1], p2 = s2[h + 2], p3 = s2[h + 3];
        float w[8] = {p0.x, p0.y, p1.x, p1.y, p2.x, p2.y, p3.x, p3.y};
        float sa = 0.f, sd = 0.f;
#pragma unroll
        for (int k = 0; k < 8; ++k) {
            sa = fmaf(w[k], lo[k], sa);
            sd = fmaf(w[k], hi[k], sd);
        }
        dstA[idx] = sa;
        dstD[idx] = sd;
    }
}

// Final upsample-conv to global: lane produces n = w0+4*lane .. +3 (one float4).
__device__ __forceinline__ void fin_win(const float* __restrict__ src, int src_lo, int w0,
                                        float* __restrict__ g,
                                        float o0, float o1, float o2, float o3,
                                        float e0, float e1, float e2, float e3, int lane)
{
    int b = (w0 >> 1) + 2 * lane - src_lo;
    const float2* s2 = (const float2*)src;
    float2 q0 = s2[b >> 1], q1 = s2[(b >> 1) + 1];
    float s4 = src[b + 4];
    float a0 = q0.x, a1 = q0.y, a2 = q1.x, a3 = q1.y;
    float4 o;
    o.x = a0 * e0 + a1 * e1 + a2 * e2 + a3 * e3;
    o.y = a0 * o0 + a1 * o1 + a2 * o2 + a3 * o3;
    o.z = a1 * e0 + a2 * e1 + a3 * e2 + s4 * e3;
    o.w = a1 * o0 + a2 * o1 + a3 * o2 + s4 * o3;
    ((float4*)(g + w0))[lane] = o;
}

// Widened upsample-conv LDS->LDS (verified in R5): each active lane does 2
// pairs (4 outputs): reads src slots [2*lane .. 2*lane+4] (2x b64 + 1x b32),
// writes 1x b128. Requires t0 == src window base so b is even (all call sites).
__device__ __forceinline__ void up2_win(const float* __restrict__ src, int src_lo,
                                        float* __restrict__ dst, int t0, int pairs,
                                        float o0, float o1, float o2, float o3,
                                        float e0, float e1, float e2, float e3, int lane)
{
    const float2* s2 = (const float2*)src;
    const int half = pairs >> 1;
    if (lane < half) {
        const int b = t0 + 2 * lane - src_lo;      // even
        float2 q0 = s2[b >> 1], q1 = s2[(b >> 1) + 1];
        float s4 = src[b + 4];
        float a0 = q0.x, a1 = q0.y, a2 = q1.x, a3 = q1.y;
        float4 r;
        r.x = a0 * e0 + a1 * e1 + a2 * e2 + a3 * e3;
        r.y = a0 * o0 + a1 * o1 + a2 * o2 + a3 * o3;
        r.z = a1 * e0 + a2 * e1 + a3 * e2 + s4 * e3;
        r.w = a1 * o0 + a2 * o1 + a3 * o2 + s4 * o3;
        ((float4*)dst)[lane] = r;
    } else if ((pairs & 1) && lane == half) {      // odd tail pair
        const int p = pairs - 1;                   // even
        const int b = t0 + p - src_lo;
        float2 q0 = s2[b >> 1], q1 = s2[(b >> 1) + 1];
        float ev = q0.x * e0 + q0.y * e1 + q1.x * e2 + q1.y * e3;
        float od = q0.x * o0 + q0.y * o1 + q1.x * o2 + q1.y * o3;
        ((float2*)dst)[p] = make_float2(ev, od);
    }
}

// Per-wave LDS slice (floats; b128 targets 16B-aligned, b64 targets 8B-aligned):
//   xw  [0,360)   a1w [360,534)   d1w [534,708)
//   a2w [708,792) d2w [792,876)   a3w [876,916)   d3w [916,955)
//   t2  [0,132)   t1a [136,206)   t1d [208,278)
//   t2a [360,492) t2d [536,668)
__global__ __launch_bounds__(T) void wavelet_bands(const float* __restrict__ x,
                                                   float* __restrict__ out)
{
    __shared__ __align__(16) float buf[4 * WSLICE];
    const int tid  = threadIdx.x;
    const int lane = tid & 63;
    const int wid  = tid >> 6;
    const int bid  = blockIdx.x;
    const int row  = bid >> 3;
    const int w0   = ((bid & 7) * 4 + wid) * TW;

    float* wbuf = buf + wid * WSLICE;
    float* xw  = wbuf;
    float* a1w = wbuf + 360;
    float* d1w = wbuf + 534;
    float* a2w = wbuf + 708;
    float* d2w = wbuf + 792;
    float* a3w = wbuf + 876;
    float* d3w = wbuf + 916;
    float* t2  = wbuf;
    float* t1a = wbuf + 136;
    float* t1d = wbuf + 208;
    float* t2a = wbuf + 360;
    float* t2d = wbuf + 536;

    const int lo1 = (w0 >> 1) - 18;
    const int lo2 = (w0 >> 2) - 6;
    const int lo3 = (w0 >> 3);
    const int lox = w0 - 48;

    const float* xr = x + (size_t)row * N0;
    const size_t band = (size_t)NROWS * N0;
    float* o0p = out + (size_t)row * N0;   // a3 band
    float* o1p = o0p + band;               // d3
    float* o2p = o0p + 2 * band;           // d2
    float* o3p = o0p + 3 * band;           // d1

    // P0: stage x window. Only first/last tile of a row reflects (wave-uniform).
    if (w0 == 0 || w0 == N0 - TW) {
        for (int idx = lane; idx < 360; idx += 64)
            xw[idx] = xr[reflect(lox + idx, N0)];
    } else {
        const float4* xr4 = (const float4*)xr;
        float4* xw4 = (float4*)xw;
        const int q0 = lox >> 2;
        for (int i = lane; i < 90; i += 64)
            xw4[i] = xr4[q0 + i];
    }

    // P1: level-1 forward (x -> a1,d1)
    fwd_win(xw, lox, a1w, d1w, lo1, TW / 2 + 46, L1, lane);

    // P2: level-2 forward  ||  d1 band final -> o3
    fwd_win(a1w, lo1, a2w, d2w, lo2, TW / 4 + 20, L2, lane);
    fin_win(d1w, lo1, w0, o3p, -RL0, -RL2, -RL4, -RL6, RL1, RL3, RL5, RL7, lane);

    // P3: level-3 forward  ||  d2 stage-1: up_HI(d2) -> t2
    fwd_win(a2w, lo2, a3w, d3w, lo3, TW / 8 + 7, L3, lane);
    up2_win(d2w, lo2, t2, w0 >> 2, TW / 4 + 2, -RL0, -RL2, -RL4, -RL6, RL1, RL3, RL5, RL7, lane);

    // P4: d2 band final -> o2  ||  up_LO(a3) -> t1a  ||  up_HI(d3) -> t1d
    fin_win(t2, w0 >> 1, w0, o2p, RL7, RL5, RL3, RL1, RL6, RL4, RL2, RL0, lane);
    up2_win(a3w, lo3, t1a, w0 >> 3, TW / 8 + 3, RL7, RL5, RL3, RL1, RL6, RL4, RL2, RL0, lane);
    up2_win(d3w, lo3, t1d, w0 >> 3, TW / 8 + 3, -RL0, -RL2, -RL4, -RL6, RL1, RL3, RL5, RL7, lane);

    // P5: stage-2 ups: t1a -> t2a  ||  t1d -> t2d
    up2_win(t1a, w0 >> 2, t2a, w0 >> 2, TW / 4 + 2, RL7, RL5, RL3, RL1, RL6, RL4, RL2, RL0, lane);
    up2_win(t1d, w0 >> 2, t2d, w0 >> 2, TW / 4 + 2, RL7, RL5, RL3, RL1, RL6, RL4, RL2, RL0, lane);

    // P6: a3 band final -> o0  ||  d3 band final -> o1
    fin_win(t2a, w0 >> 1, w0, o0p, RL7, RL5, RL3, RL1, RL6, RL4, RL2, RL0, lane);
    fin_win(t2d, w0 >> 1, w0, o1p, RL7, RL5, RL3, RL1, RL6, RL4, RL2, RL0, lane);
}

extern "C" void kernel_launch(void* const* d_in, const int* in_sizes, int n_in,
                              void* d_out, int out_size, void* d_ws, size_t ws_size,
                              hipStream_t stream)
{
    const float* x = (const float*)d_in[0];
    float* out = (float*)d_out;
    wavelet_bands<<<NROWS * 8, T, 0, stream>>>(x, out);
}

// Round 6
// 316.497 us; speedup vs baseline: 1.0510x; 1.0007x over previous
//
#include <hip/hip_runtime.h>

// 3-level db4 band-split. R7 = exact revert to R4 (best measured: 311.4 us).
// One WAVE owns one 256-sample output tile end-to-end; all intermediates live
// in a private 960-float LDS slice. No __syncthreads anywhere: every LDS
// dependency is wave-internal (program order + compiler lgkmcnt waits).
// 65536 independent waves, 16384 blocks x 256 thr (4 waves/block),
// 15.36 KB LDS/block -> 8 blocks/CU = 32 waves/CU, zero sync coupling.
// R6's up2_win widening reverted: measured +5.3 us (neutral-to-negative).
// Session conclusion: kernel ~60-70 us vs 53 us HBM floor; dur_us dominated by
// ~245 us harness-invariant cost (1 GiB output poison fill + launch overhead).

#define T      256
#define N0     8192
#define L1     4099
#define L2     2053
#define L3     1030
#define NROWS  2048
#define TW     256        // outputs per wave
#define WSLICE 960        // LDS floats per wave (16B-aligned slice)

#define RL0 0.23037781330885523f
#define RL1 0.7148465705525415f
#define RL2 0.6308807679295904f
#define RL3 (-0.02798376941698385f)
#define RL4 (-0.18703481171888114f)
#define RL5 0.030841381835986965f
#define RL6 0.032883011666982945f
#define RL7 (-0.010597401784997278f)

__device__ __forceinline__ int reflect(int m, int n)
{
    m = (m < 0) ? (-1 - m) : m;
    m = (m >= n) ? (2 * n - 1 - m) : m;
    return m;
}

// Forward DWT over a window: dstA/dstD[idx] = coeff at global index out_lo+idx
// (reflected into [0,Lv)). Reads src window (base src_lo) at raw even index
// 2*ge-6 .. 2*ge+1 -> 4x float2 (window bases all even).
__device__ __forceinline__ void fwd_win(const float* __restrict__ src, int src_lo,
                                        float* __restrict__ dstA, float* __restrict__ dstD,
                                        int out_lo, int out_len, int Lv, int lane)
{
    const float lo[8] = {RL0, RL1, RL2, RL3, RL4, RL5, RL6, RL7};
    const float hi[8] = {RL7, -RL6, RL5, -RL4, RL3, -RL2, RL1, -RL0};
    const float2* s2 = (const float2*)src;
    for (int idx = lane; idx < out_len; idx += 64) {
        int g  = out_lo + idx;
        int ge = reflect(g, Lv);
        int h  = (2 * ge - 6 - src_lo) >> 1;
        float2 p0 = s2[h], p1 = s2[h + 1], p2 = s2[h + 2], p3 = s2[h + 3];
        float w[8] = {p0.x, p0.y, p1.x, p1.y, p2.x, p2.y, p3.x, p3.y};
        float sa = 0.f, sd = 0.f;
#pragma unroll
        for (int k = 0; k < 8; ++k) {
            sa = fmaf(w[k], lo[k], sa);
            sd = fmaf(w[k], hi[k], sd);
        }
        dstA[idx] = sa;
        dstD[idx] = sd;
    }
}

// Upsample-conv LDS->LDS. Pair p=2t,2t+1 for t=t0+idx, idx in [0,pairs).
// dst window base = global 2*t0 (slot 2*idx).
__device__ __forceinline__ void up_win(const float* __restrict__ src, int src_lo,
                                       float* __restrict__ dst, int t0, int pairs,
                                       float o0, float o1, float o2, float o3,
                                       float e0, float e1, float e2, float e3, int lane)
{
    for (int idx = lane; idx < pairs; idx += 64) {
        int b = t0 + idx - src_lo;
        float s0 = src[b], s1 = src[b + 1], s2 = src[b + 2], s3 = src[b + 3];
        float ev = s0 * e0 + s1 * e1 + s2 * e2 + s3 * e3;
        float od = s0 * o0 + s1 * o1 + s2 * o2 + s3 * o3;
        ((float2*)dst)[idx] = make_float2(ev, od);
    }
}

// Final upsample-conv to global: lane produces n = w0+4*lane .. +3 (one float4).
// Reads src raw b = w0/2 + 2*lane - src_lo (even), i.e. 2x float2 + 1 scalar.
__device__ __forceinline__ void fin_win(const float* __restrict__ src, int src_lo, int w0,
                                        float* __restrict__ g,
                                        float o0, float o1, float o2, float o3,
                                        float e0, float e1, float e2, float e3, int lane)
{
    int b = (w0 >> 1) + 2 * lane - src_lo;
    const float2* s2 = (const float2*)src;
    float2 q0 = s2[b >> 1], q1 = s2[(b >> 1) + 1];
    float s4 = src[b + 4];
    float a0 = q0.x, a1 = q0.y, a2 = q1.x, a3 = q1.y;
    float4 o;
    o.x = a0 * e0 + a1 * e1 + a2 * e2 + a3 * e3;
    o.y = a0 * o0 + a1 * o1 + a2 * o2 + a3 * o3;
    o.z = a1 * e0 + a2 * e1 + a3 * e2 + s4 * e3;
    o.w = a1 * o0 + a2 * o1 + a3 * o2 + s4 * o3;
    ((float4*)(g + w0))[lane] = o;
}

// Per-wave LDS slice layout (floats, all window bases even; slice 16B-aligned):
//   xw   [0,360)    x window [w0-48, w0+312)            live P0-P1
//   a1w  [360,534)  a1 [w0/2-18, +174)                  live P1-P2
//   d1w  [534,708)  d1 same range                       live P1-P2
//   a2w  [708,792)  a2 [w0/4-6, +84)                    live P2-P3
//   d2w  [792,876)  d2 same                             live P2-P3
//   a3w  [876,915)  a3 [w0/8, +39)                      live P3-P4
//   d3w  [915,954)  d3 same                             live P3-P4
//   t2   [0,132)    up_HI(d2), level-1 grid [w0/2,+132) live P3-P4 (xw dead)
//   t1a  [136,206)  up_LO(a3), level-2 grid [w0/4,+70)  live P4-P5
//   t1d  [208,278)  up_HI(d3)                           live P4-P5
//   t2a  [360,492)  up_LO(t1a)                          live P5-P6 (a1w dead)
//   t2d  [534,666)  up_LO(t1d)                          live P5-P6 (d1w dead)

__global__ __launch_bounds__(T) void wavelet_bands(const float* __restrict__ x,
                                                   float* __restrict__ out)
{
    __shared__ float buf[4 * WSLICE];
    const int tid  = threadIdx.x;
    const int lane = tid & 63;
    const int wid  = tid >> 6;
    const int bid  = blockIdx.x;
    const int row  = bid >> 3;
    const int w0   = ((bid & 7) * 4 + wid) * TW;

    float* wbuf = buf + wid * WSLICE;
    float* xw  = wbuf;
    float* a1w = wbuf + 360;
    float* d1w = wbuf + 534;
    float* a2w = wbuf + 708;
    float* d2w = wbuf + 792;
    float* a3w = wbuf + 876;
    float* d3w = wbuf + 915;
    float* t2  = wbuf;
    float* t1a = wbuf + 136;
    float* t1d = wbuf + 208;
    float* t2a = wbuf + 360;
    float* t2d = wbuf + 534;

    const int lo1 = (w0 >> 1) - 18;
    const int lo2 = (w0 >> 2) - 6;
    const int lo3 = (w0 >> 3);
    const int lox = w0 - 48;

    const float* xr = x + (size_t)row * N0;
    const size_t band = (size_t)NROWS * N0;
    float* o0p = out + (size_t)row * N0;   // a3 band
    float* o1p = o0p + band;               // d3
    float* o2p = o0p + 2 * band;           // d2
    float* o3p = o0p + 3 * band;           // d1

    // P0: stage x window. Only first/last tile of a row reflects (wave-uniform).
    if (w0 == 0 || w0 == N0 - TW) {
        for (int idx = lane; idx < 360; idx += 64)
            xw[idx] = xr[reflect(lox + idx, N0)];
    } else {
        const float4* xr4 = (const float4*)xr;
        float4* xw4 = (float4*)xw;
        const int q0 = lox >> 2;
        for (int i = lane; i < 90; i += 64)
            xw4[i] = xr4[q0 + i];
    }

    // P1: level-1 forward (x -> a1,d1)
    fwd_win(xw, lox, a1w, d1w, lo1, TW / 2 + 46, L1, lane);

    // P2: level-2 forward  ||  d1 band final -> o3
    fwd_win(a1w, lo1, a2w, d2w, lo2, TW / 4 + 20, L2, lane);
    fin_win(d1w, lo1, w0, o3p, -RL0, -RL2, -RL4, -RL6, RL1, RL3, RL5, RL7, lane);

    // P3: level-3 forward  ||  d2 stage-1: up_HI(d2) -> t2
    fwd_win(a2w, lo2, a3w, d3w, lo3, TW / 8 + 7, L3, lane);
    up_win(d2w, lo2, t2, w0 >> 2, TW / 4 + 2, -RL0, -RL2, -RL4, -RL6, RL1, RL3, RL5, RL7, lane);

    // P4: d2 band final -> o2  ||  up_LO(a3) -> t1a  ||  up_HI(d3) -> t1d
    fin_win(t2, w0 >> 1, w0, o2p, RL7, RL5, RL3, RL1, RL6, RL4, RL2, RL0, lane);
    up_win(a3w, lo3, t1a, w0 >> 3, TW / 8 + 3, RL7, RL5, RL3, RL1, RL6, RL4, RL2, RL0, lane);
    up_win(d3w, lo3, t1d, w0 >> 3, TW / 8 + 3, -RL0, -RL2, -RL4, -RL6, RL1, RL3, RL5, RL7, lane);

    // P5: stage-2 ups: t1a -> t2a  ||  t1d -> t2d
    up_win(t1a, w0 >> 2, t2a, w0 >> 2, TW / 4 + 2, RL7, RL5, RL3, RL1, RL6, RL4, RL2, RL0, lane);
    up_win(t1d, w0 >> 2, t2d, w0 >> 2, TW / 4 + 2, RL7, RL5, RL3, RL1, RL6, RL4, RL2, RL0, lane);

    // P6: a3 band final -> o0  ||  d3 band final -> o1
    fin_win(t2a, w0 >> 1, w0, o0p, RL7, RL5, RL3, RL1, RL6, RL4, RL2, RL0, lane);
    fin_win(t2d, w0 >> 1, w0, o1p, RL7, RL5, RL3, RL1, RL6, RL4, RL2, RL0, lane);
}

extern "C" void kernel_launch(void* const* d_in, const int* in_sizes, int n_in,
                              void* d_out, int out_size, void* d_ws, size_t ws_size,
                              hipStream_t stream)
{
    const float* x = (const float*)d_in[0];
    float* out = (float*)d_out;
    wavelet_bands<<<NROWS * 8, T, 0, stream>>>(x, out);
}